// Round 4
// baseline (1512.328 us; speedup 1.0000x reference)
//
#include <hip/hip_runtime.h>
#include <math.h>

#define B_ 32
#define S_ 256
#define H_ 2048
#define NH_ 16
#define HD_ 128
#define M_ (B_*S_)
#define K_ H_

typedef unsigned short u16;
typedef unsigned int   u32;
typedef __attribute__((ext_vector_type(8))) short  short8;   // 8 bf16 (4 VGPRs) MFMA A/B frag
typedef __attribute__((ext_vector_type(8))) unsigned short ushort8;
typedef __attribute__((ext_vector_type(4))) float  floatx4;  // MFMA C/D frag

typedef __attribute__((address_space(3))) u32 lds_u32;
typedef __attribute__((address_space(1))) const u32 glb_u32;

__device__ __forceinline__ u16 rne_bf16(float f) {
    u32 u = __float_as_uint(f);
    return (u16)((u + 0x7fffu + ((u >> 16) & 1u)) >> 16);
}
__device__ __forceinline__ float bf16_to_f(u16 h) {
    return __uint_as_float(((u32)h) << 16);
}
__device__ __forceinline__ void gll16(const u16* g, u16* l) {
    __builtin_amdgcn_global_load_lds((glb_u32*)g, (lds_u32*)l, 16, 0, 0);
}

// ---------------------------------------------------------------------------
// X fp32 -> bf16 (hi only; error budget: dropped lo-term is below bf16 QKV noise)
// ---------------------------------------------------------------------------
__global__ __launch_bounds__(256) void cvt_bf16(const float* __restrict__ x,
                                                u16* __restrict__ hi, int n4)
{
    int i = blockIdx.x * 256 + threadIdx.x;
    if (i >= n4) return;
    float4 v = ((const float4*)x)[i];
    ((ushort4*)hi)[i] = make_ushort4(rne_bf16(v.x), rne_bf16(v.y), rne_bf16(v.z), rne_bf16(v.w));
}

// ---------------------------------------------------------------------------
// W fp32 -> (hi, lo) bf16 split, all 4 weights in one launch (grid.y = which W)
// ---------------------------------------------------------------------------
__global__ __launch_bounds__(256) void split_w(
    const float* __restrict__ w0, const float* __restrict__ w1,
    const float* __restrict__ w2, const float* __restrict__ w3,
    u16* __restrict__ dst)
{
    int wi = blockIdx.y;
    const float* wsrc = (wi == 0) ? w0 : (wi == 1) ? w1 : (wi == 2) ? w2 : w3;
    int i = blockIdx.x * 256 + threadIdx.x;          // < 2048*2048/4
    float4 v = ((const float4*)wsrc)[i];
    float vv[4] = {v.x, v.y, v.z, v.w};
    u16 h[4], l[4];
#pragma unroll
    for (int j = 0; j < 4; ++j) {
        h[j] = rne_bf16(vv[j]);
        l[j] = rne_bf16(vv[j] - bf16_to_f(h[j]));
    }
    u16* hip_ = dst + (size_t)(2*wi)   * 4194304;
    u16* lop_ = dst + (size_t)(2*wi+1) * 4194304;
    ((ushort4*)hip_)[i] = make_ushort4(h[0], h[1], h[2], h[3]);
    ((ushort4*)lop_)[i] = make_ushort4(l[0], l[1], l[2], l[3]);
}

// ---------------------------------------------------------------------------
// C = A @ (Bhi+Blo)^T, 2-pass bf16 MFMA, fp32 acc. A:[M,2048] bf16, B:[2048,2048].
// 128x128 tile, BK=32, 4 waves, wave tile 64x64 (4x4 mfma 16x16x32), 24KB LDS.
// 1D grid 1024, XCD-aware decode: xcd=id&7 owns a 16(by) x 8(bx) rectangle.
// mode 0: bf16 head-major [B,NH,S,HD] (bx == head). mode 1: fp32 [M,2048].
// Single LDS arena + offset arithmetic (runtime-indexed LDS ptr arrays don't compile).
// ---------------------------------------------------------------------------
__global__ __launch_bounds__(256, 3) void gemm_2p(
    const u16* __restrict__ A,
    const u16* __restrict__ Bhi, const u16* __restrict__ Blo,
    void* __restrict__ outv, int mode)
{
    __shared__ u16 smem[12288];   // [0:4096)=sA, [4096:8192)=sBhi, [8192:12288)=sBlo

    const int tid = threadIdx.x;
    const int lane = tid & 63, w = tid >> 6;
    const int wm = w >> 1, wn = w & 1;
    const int r15 = lane & 15, quad = lane >> 4;

    // XCD swizzle: dispatch round-robins id%8 across XCDs
    const int lid = blockIdx.x;
    const int xcd = lid & 7, sub = lid >> 3;           // sub: 0..127
    const int bx = ((xcd & 1) << 3) + (sub & 7);       // 0..15
    const int by = ((xcd >> 1) << 4) + (sub >> 3);     // 0..63

    const u16* baseA  = A   + (size_t)by * 128 * K_;
    const u16* baseBh = Bhi + (size_t)bx * 128 * K_;
    const u16* baseBl = Blo + (size_t)bx * 128 * K_;

    const u16* gp[6];
    u16*       lp[6];
#pragma unroll
    for (int t = 0; t < 6; ++t) {
        int s = w*6 + t;                 // 0..23 wave-uniform segment
        int buf = s >> 3, segi = s & 7;  // buf: 0=A 1=Bhi 2=Blo
        int chunk = segi*64 + lane;      // 0..511 == kc*128 + row
        int kc = chunk >> 7, row = chunk & 127;
        const u16* gb = (buf == 0) ? baseA : (buf == 1) ? baseBh : baseBl;
        gp[t] = gb + (size_t)row * K_ + kc*8;
        lp[t] = smem + buf*4096 + segi*512;   // wave-uniform base; lanes spread *16B
    }

    const floatx4 fzero = {0.f, 0.f, 0.f, 0.f};
    floatx4 acc[4][4];
#pragma unroll
    for (int mi = 0; mi < 4; ++mi)
#pragma unroll
        for (int ni = 0; ni < 4; ++ni) acc[mi][ni] = fzero;

    for (int kt = 0; kt < K_/32; ++kt) {
#pragma unroll
        for (int t = 0; t < 6; ++t) {
            gll16(gp[t], lp[t]);
            gp[t] += 32;
        }
        __syncthreads();

        short8 a[4], bh[4], bl[4];
#pragma unroll
        for (int mi = 0; mi < 4; ++mi)
            a[mi] = *(const short8*)&smem[(quad*128 + wm*64 + mi*16 + r15) * 8];
#pragma unroll
        for (int ni = 0; ni < 4; ++ni) {
            int idx = (quad*128 + wn*64 + ni*16 + r15) * 8;
            bh[ni] = *(const short8*)&smem[4096*8/8 + idx];      // sBhi
            bl[ni] = *(const short8*)&smem[8192 + idx];          // sBlo
        }
#pragma unroll
        for (int mi = 0; mi < 4; ++mi)
#pragma unroll
            for (int ni = 0; ni < 4; ++ni) {
                acc[mi][ni] = __builtin_amdgcn_mfma_f32_16x16x32_bf16(a[mi], bh[ni], acc[mi][ni], 0, 0, 0);
                acc[mi][ni] = __builtin_amdgcn_mfma_f32_16x16x32_bf16(a[mi], bl[ni], acc[mi][ni], 0, 0, 0);
            }
        __syncthreads();
    }

    // C/D layout: col = lane&15, row = quad*4 + reg
    if (mode == 0) {
        u16* out = (u16*)outv;          // [B, NH, S, HD], head h == bx
#pragma unroll
        for (int mi = 0; mi < 4; ++mi)
#pragma unroll
            for (int r = 0; r < 4; ++r) {
                int m = by*128 + wm*64 + mi*16 + quad*4 + r;
                int bb = m >> 8, ss = m & 255;
                size_t base = (((size_t)(bb*NH_ + bx)) * S_ + ss) * HD_ + wn*64 + r15;
#pragma unroll
                for (int ni = 0; ni < 4; ++ni)
                    out[base + ni*16] = rne_bf16(acc[mi][ni][r]);
            }
    } else {
        float* out = (float*)outv;      // [M, 2048]
#pragma unroll
        for (int mi = 0; mi < 4; ++mi)
#pragma unroll
            for (int r = 0; r < 4; ++r) {
                int m = by*128 + wm*64 + mi*16 + quad*4 + r;
                size_t base = (size_t)m * H_ + bx*128 + wn*64 + r15;
#pragma unroll
                for (int ni = 0; ni < 4; ++ni)
                    out[base + ni*16] = acc[mi][ni][r];
            }
    }
}

// ---------------------------------------------------------------------------
// RoPE in-place on bf16 q,k in [B,NH,S,HD]; pair (i, i+64).
// ---------------------------------------------------------------------------
__global__ __launch_bounds__(256) void rope_bf(u16* __restrict__ q, u16* __restrict__ k)
{
    int idx = blockIdx.x * 256 + threadIdx.x;
    u16* p = blockIdx.y ? k : q;
    int i  = idx & 63;
    int s  = (idx >> 6) & (S_ - 1);
    int bh = idx >> 14;
    size_t base = ((size_t)bh * S_ + s) * HD_;
    float f = expf((float)i * -0.14391156831212788f);   // 10000^(-i/64)
    float ang = (float)s * f;
    float c = cosf(ang), sn = sinf(ang);
    float x0 = bf16_to_f(p[base + i]), x1 = bf16_to_f(p[base + i + 64]);
    p[base + i]      = rne_bf16(x0 * c - x1 * sn);
    p[base + i + 64] = rne_bf16(x1 * c + x0 * sn);
}

// ---------------------------------------------------------------------------
// Attention, bf16 MFMA. Block = 4 waves, one (b,h) x 64 q-rows. Scores in
// C-layout regs; softmax via 16-lane shuffle; P -> LDS plane-major -> A-frag.
// Output: plain bf16 att [M, 2048] (row m = b*256+s, col = h*128+d).
// ---------------------------------------------------------------------------
#define SCALE 0.08838834764831845f

__global__ __launch_bounds__(256) void attn_mfma(
    const u16* __restrict__ Q, const u16* __restrict__ K, const u16* __restrict__ V,
    u16* __restrict__ Oatt)
{
    __shared__ u16 shQK[16384];
    __shared__ u16 shV[8192];
    u16* Qs = shQK;            // planes [16][64] chunks of 8 bf16
    u16* Ks = shQK + 8192;
    u16* Pb = shQK;            // planes [32][64] (after Qs/Ks dead)

    const int tid = threadIdx.x;
    const int lane = tid & 63, w = tid >> 6;
    const int r15 = lane & 15, quad = lane >> 4;
    const int bh = blockIdx.x;
    const int q0 = blockIdx.y << 6;
    const int wq = w * 16;

    const u16* Qg = Q + ((size_t)bh * S_ + q0) * HD_;
    const u16* Kg = K + (size_t)bh * S_ * HD_;
    const u16* Vg = V + (size_t)bh * S_ * HD_;

#pragma unroll
    for (int p = 0; p < 4; ++p) {
        int task = tid + (p << 8);
        int r = task & 63, c = task >> 6;
        *(uint4*)&Qs[(c*64 + r)*8] = *(const uint4*)&Qg[(size_t)r*HD_ + c*8];
    }

    const floatx4 fzero = {0.f, 0.f, 0.f, 0.f};
    floatx4 sc[4][4];
    for (int kt = 0; kt < 4; ++kt) {
        __syncthreads();
#pragma unroll
        for (int p = 0; p < 4; ++p) {
            int task = tid + (p << 8);
            int r = task & 63, c = task >> 6;
            *(uint4*)&Ks[(c*64 + r)*8] = *(const uint4*)&Kg[(size_t)(kt*64 + r)*HD_ + c*8];
        }
        __syncthreads();
#pragma unroll
        for (int ni = 0; ni < 4; ++ni) sc[kt][ni] = fzero;
#pragma unroll
        for (int ks = 0; ks < 4; ++ks) {
            short8 a = *(const short8*)&Qs[((ks*4 + quad)*64 + wq + r15)*8];
#pragma unroll
            for (int ni = 0; ni < 4; ++ni) {
                short8 b = *(const short8*)&Ks[((ks*4 + quad)*64 + ni*16 + r15)*8];
                sc[kt][ni] = __builtin_amdgcn_mfma_f32_16x16x32_bf16(a, b, sc[kt][ni], 0, 0, 0);
            }
        }
    }
    __syncthreads();

#pragma unroll
    for (int kt = 0; kt < 4; ++kt)
#pragma unroll
        for (int ni = 0; ni < 4; ++ni) sc[kt][ni] *= SCALE;

    float rinv4[4], mrow4[4];
#pragma unroll
    for (int r = 0; r < 4; ++r) {
        float m = -1e30f;
#pragma unroll
        for (int kt = 0; kt < 4; ++kt)
#pragma unroll
            for (int ni = 0; ni < 4; ++ni) m = fmaxf(m, sc[kt][ni][r]);
#pragma unroll
        for (int o = 1; o < 16; o <<= 1) m = fmaxf(m, __shfl_xor(m, o));
        mrow4[r] = m;
    }
#pragma unroll
    for (int r = 0; r < 4; ++r) {
        float ssum = 0.f;
#pragma unroll
        for (int kt = 0; kt < 4; ++kt)
#pragma unroll
            for (int ni = 0; ni < 4; ++ni) {
                float e = __expf(sc[kt][ni][r] - mrow4[r]);
                sc[kt][ni][r] = e;
                ssum += e;
            }
#pragma unroll
        for (int o = 1; o < 16; o <<= 1) ssum += __shfl_xor(ssum, o);
        rinv4[r] = 1.f / ssum;
    }
#pragma unroll
    for (int r = 0; r < 4; ++r) {
        int row = wq + quad*4 + r;
#pragma unroll
        for (int kt = 0; kt < 4; ++kt)
#pragma unroll
            for (int ni = 0; ni < 4; ++ni) {
                int col = kt*64 + ni*16 + r15;
                Pb[((col >> 3)*64 + row)*8 + (col & 7)] = rne_bf16(sc[kt][ni][r] * rinv4[r]);
            }
    }

    floatx4 oacc[8];
#pragma unroll
    for (int di = 0; di < 8; ++di) oacc[di] = fzero;

    for (int vt = 0; vt < 4; ++vt) {
        __syncthreads();
#pragma unroll
        for (int p = 0; p < 4; ++p) {
            int task = tid + (p << 8);
            int r = task & 63, dc = task >> 6;
            ushort8 v = *(const ushort8*)&Vg[(size_t)(vt*64 + r)*HD_ + dc*8];
#pragma unroll
            for (int j = 0; j < 8; ++j)
                shV[(((r >> 3)*128) + dc*8 + j)*8 + (r & 7)] = v[j];
        }
        __syncthreads();
#pragma unroll
        for (int ks = 0; ks < 2; ++ks) {
            int colbase = vt*64 + ks*32 + quad*8;
            short8 a = *(const short8*)&Pb[((colbase >> 3)*64 + wq + r15)*8];
            int sp = ks*32 + quad*8;
#pragma unroll
            for (int di = 0; di < 8; ++di) {
                short8 b = *(const short8*)&shV[((sp >> 3)*128 + di*16 + r15)*8];
                oacc[di] = __builtin_amdgcn_mfma_f32_16x16x32_bf16(a, b, oacc[di], 0, 0, 0);
            }
        }
    }

    const int brow = bh >> 4, h = bh & 15;
#pragma unroll
    for (int r = 0; r < 4; ++r) {
        size_t base = ((size_t)(brow*S_ + q0 + wq + quad*4 + r)) * H_ + h*128 + r15;
#pragma unroll
        for (int di = 0; di < 8; ++di)
            Oatt[base + di*16] = rne_bf16(oacc[di][r]);
    }
}

// ---------------------------------------------------------------------------
extern "C" void kernel_launch(void* const* d_in, const int* in_sizes, int n_in,
                              void* d_out, int out_size, void* d_ws, size_t ws_size,
                              hipStream_t stream)
{
    const float* X  = (const float*)d_in[0];
    float* outp = (float*)d_out;

    char* ws = (char*)d_ws;
    u16* Xbf = (u16*)ws;                          //  33.5 MB  [M, 2048]
    u16* Wsp = (u16*)(ws + 33554432);             //  8 x 8.4 MB (hi/lo per W)
    u16* Qbf = (u16*)(ws + 100663296);            //  [B,NH,S,HD]
    u16* Kbf = (u16*)(ws + 134217728);
    u16* Vbf = (u16*)(ws + 167772160);
    u16* Att = (u16*)(ws + 201326592);            //  [M, 2048]; end 235 MB

    cvt_bf16<<<M_*H_/4/256, 256, 0, stream>>>(X, Xbf, M_*H_/4);
    split_w<<<dim3(H_*H_/4/256, 4), 256, 0, stream>>>(
        (const float*)d_in[1], (const float*)d_in[2],
        (const float*)d_in[3], (const float*)d_in[4], Wsp);

    gemm_2p<<<1024, 256, 0, stream>>>(Xbf, Wsp + (size_t)0*4194304, Wsp + (size_t)1*4194304, Qbf, 0);
    gemm_2p<<<1024, 256, 0, stream>>>(Xbf, Wsp + (size_t)2*4194304, Wsp + (size_t)3*4194304, Kbf, 0);
    gemm_2p<<<1024, 256, 0, stream>>>(Xbf, Wsp + (size_t)4*4194304, Wsp + (size_t)5*4194304, Vbf, 0);
    rope_bf<<<dim3(32768, 2), 256, 0, stream>>>(Qbf, Kbf);
    attn_mfma<<<dim3(B_*NH_, 4), 256, 0, stream>>>(Qbf, Kbf, Vbf, Att);
    gemm_2p<<<1024, 256, 0, stream>>>(Att, Wsp + (size_t)6*4194304, Wsp + (size_t)7*4194304, outp, 1);
}